// Round 4
// baseline (1804.501 us; speedup 1.0000x reference)
//
#include <hip/hip_runtime.h>
#include <cstdint>

// AdaptiveNet: x[16384,1024] -> fc1(4096)+sigmoid -> grouped(512 g of 8)+sigmoid -> fc3(256)
// R5: fp8-e4m3 GEMM1 (W1 x64, acc/64), BK=128, 164us. VGPR=64 (acc in AGPRs).
// R6: MX-scaled builtin, 4-wave 64x64/wave: acc forced into VGPRs -> spill, 1086us.
// R7: no-cap variant: VGPR=256, 1 wave/SIMD, 378us. Lesson: mfma_scale acc lives in
//     arch VGPRs; 64-reg acc + 40-reg frags can't fit 128-cap. Allocation hints can't fix it.
// R8: inline-asm non-scaled K=128 MFMA -> container died twice; untested opcode form, binned.
// R9: scaled builtin (HW-verified R6/R7) + STRUCTURAL pressure fix: 512 threads,
//     8 waves of 64x32 output -> acc[4][2]=32 VGPR, ~105 total, launch_bounds(512,4)
//     caps 128 VGPR = 16 waves/CU. Same 128x128 tile, same staging geometry
//     (2 chunks/wave/matrix), same verified fragment formulas and epilogue.

#define B_ROWS 16384
#define DIN 1024
#define H1  4096
#define H2  512
#define DOUT 256
#define TILE 128
#define BK 64          // bf16 core (gemm3)
#define BK1 128        // fp8 core (gemm1)
#define INV_W1SCALE 0.015625f   // 1/64
#define SCALE_ONE 0x7F7F7F7F    // E8M0 127 = 2^0 in every byte (opsel-proof)

#define NX4  (B_ROWS * DIN / 4)   // 4194304
#define NW14 (H1 * DIN / 4)       // 1048576
#define NW34 (DOUT * H2 / 4)      // 32768

typedef __bf16 bf16x8 __attribute__((ext_vector_type(8)));
typedef float f32x4 __attribute__((ext_vector_type(4)));
typedef int   i32x4 __attribute__((ext_vector_type(4)));
typedef int   i32x8 __attribute__((ext_vector_type(8)));

__device__ __forceinline__ unsigned short f2bf(float f) {
    union { float f; uint32_t u; } v; v.f = f;
    uint32_t u = v.u;
    u += 0x7FFFu + ((u >> 16) & 1u);   // round-to-nearest-even
    return (unsigned short)(u >> 16);
}

__device__ __forceinline__ float sigmoidf_fast(float x) {
    return 1.0f / (1.0f + __expf(-x));
}

// x -> fp8 (x1), W1 -> fp8 (x64), W3 -> bf16, one launch
__global__ __launch_bounds__(256) void cvt3_kernel(
    const float* __restrict__ x, const float* __restrict__ w1,
    const float* __restrict__ w3, unsigned int* __restrict__ xo,
    unsigned int* __restrict__ w1o, unsigned short* __restrict__ w3o) {
    int i = blockIdx.x * 256 + threadIdx.x;
    if (i < NX4) {
        float4 v = ((const float4*)x)[i];
        unsigned int p = 0;
        p = __builtin_amdgcn_cvt_pk_fp8_f32(v.x, v.y, p, false);
        p = __builtin_amdgcn_cvt_pk_fp8_f32(v.z, v.w, p, true);
        xo[i] = p;
    } else if (i < NX4 + NW14) {
        int j = i - NX4;
        float4 v = ((const float4*)w1)[j];
        unsigned int p = 0;
        p = __builtin_amdgcn_cvt_pk_fp8_f32(v.x * 64.0f, v.y * 64.0f, p, false);
        p = __builtin_amdgcn_cvt_pk_fp8_f32(v.z * 64.0f, v.w * 64.0f, p, true);
        w1o[j] = p;
    } else {
        int j = i - NX4 - NW14;
        float4 v = ((const float4*)w3)[j];
        ushort4 o;
        o.x = f2bf(v.x); o.y = f2bf(v.y); o.z = f2bf(v.z); o.w = f2bf(v.w);
        ((ushort4*)w3o)[j] = o;
    }
}

__device__ __forceinline__ void load_lds16(const void* g, void* l) {
    __builtin_amdgcn_global_load_lds(
        (const __attribute__((address_space(1))) void*)g,
        (__attribute__((address_space(3))) void*)l, 16, 0, 0);
}

// Assemble a 32B MX operand (K=128: lane holds k = q*32 .. q*32+31 of its row)
// from two rotated 16B LDS slots.
__device__ __forceinline__ i32x8 ld_frag(const unsigned char* base, int a0, int a1) {
    i32x4 lo = *(const i32x4*)(base + a0);
    i32x4 hi = *(const i32x4*)(base + a1);
    return __builtin_shufflevector(lo, hi, 0, 1, 2, 3, 4, 5, 6, 7);
}

// ---------------- MX-fp8 core, BK1=128, tile 128x128, 8 waves ----------------
// LDS row = 128 fp8 = 128B = 8 chunks of 16B, chunk slots rotated by (row&7).
// Wave grid: 2 rows x 4 cols of 64x32 output sub-tiles.
// A-frag (16x16x128 f8f6f4): lane(q=l>>4,m=l&15) holds 32 consecutive fp8 at
// k=q*32 of row m: data slots {2q, 2q+1}, physical slot = (dataslot + (m&7)) & 7.
// (Layout HW-verified in R6/R7.)
__global__ __launch_bounds__(512, 4) void gemm1_fused(
    const unsigned char* __restrict__ Xq,    // [16384,1024] fp8
    const unsigned char* __restrict__ W1q,   // [4096,1024]  fp8 (N,K), x64
    const float* __restrict__ b1,            // [4096]
    const float* __restrict__ W2,            // [512*8] flat; W2[g][s] = W2[gn]
    const float* __restrict__ b2,            // [512]
    unsigned short* __restrict__ X2) {       // [16384,512] bf16
    __shared__ __attribute__((aligned(16))) unsigned char lsA[TILE * BK1];
    __shared__ __attribute__((aligned(16))) unsigned char lsB[TILE * BK1];
    const int tid = threadIdx.x, lane = tid & 63, wave = tid >> 6;
    const int wm = (wave >> 2) * 64;     // 2 wave-rows of 64
    const int wn = (wave & 3) * 32;      // 4 wave-cols of 32

    // XCD-aware decode (R4): xcd owns a 512-col W1 slice (L2-resident)
    const int bid = blockIdx.x;
    const int xcd = bid & 7;
    const int local = bid >> 3;
    const int n0 = (xcd * 4 + (local & 3)) * TILE;
    const int a0 = (local >> 2) * TILE;

    const int q = lane >> 4, m16 = lane & 15;

    // staging: 2 chunks of 1KB per matrix per wave; chunk = 8 rows x 128B
    int gA[2], gB[2], lo[2];
#pragma unroll
    for (int i = 0; i < 2; ++i) {
        const int ch = wave * 2 + i;                 // 0..15
        const int r  = ch * 8 + (lane >> 3);
        const int kc = ((lane & 7) - (lane >> 3)) & 7;
        gA[i] = (a0 + r) * DIN + kc * 16;
        gB[i] = (n0 + r) * DIN + kc * 16;
        lo[i] = ch * 1024;
    }
    // fragment addresses: per 16-row block, the two rotated 16B slots of
    // this lane's 32B k-chunk (data slots 2q and 2q+1, rotation by row&7=m16&7)
    const int rot = m16 & 7;
    const int p0 = (2 * q + rot) & 7;
    const int p1 = (2 * q + 1 + rot) & 7;
    int aA0[4], aA1[4], aB0[2], aB1[2];
#pragma unroll
    for (int t = 0; t < 4; ++t) {
        const int ra = (wm + t * 16 + m16) * BK1;
        aA0[t] = ra + p0 * 16; aA1[t] = ra + p1 * 16;
    }
#pragma unroll
    for (int t = 0; t < 2; ++t) {
        const int rb = (wn + t * 16 + m16) * BK1;
        aB0[t] = rb + p0 * 16; aB1[t] = rb + p1 * 16;
    }

    f32x4 acc[4][2];
#pragma unroll
    for (int r = 0; r < 4; ++r)
#pragma unroll
        for (int c = 0; c < 2; ++c) acc[r][c] = (f32x4)0.0f;

    for (int kt = 0; kt < DIN / BK1; ++kt) {
        __syncthreads();
        const int k0 = kt * BK1;
#pragma unroll
        for (int i = 0; i < 2; ++i) {
            load_lds16(Xq + gA[i] + k0, lsA + lo[i]);
            load_lds16(W1q + gB[i] + k0, lsB + lo[i]);
        }
        __syncthreads();
        i32x8 af[4];
#pragma unroll
        for (int t = 0; t < 4; ++t)
            af[t] = ld_frag(lsA, aA0[t], aA1[t]);
#pragma unroll
        for (int c = 0; c < 2; ++c) {
            const i32x8 bf = ld_frag(lsB, aB0[c], aB1[c]);
#pragma unroll
            for (int r = 0; r < 4; ++r)
                acc[r][c] = __builtin_amdgcn_mfma_scale_f32_16x16x128_f8f6f4(
                    af[r], bf, acc[r][c], 0, 0, 0, SCALE_ONE, 0, SCALE_ONE);
        }
    }

    // Epilogue. C/D layout: col = lane&15, row = (lane>>4)*4 + reg. acc is 64x true z1.
#pragma unroll
    for (int c = 0; c < 2; ++c) {
        const int gn = n0 + wn + c * 16 + m16;        // h column
        const float w2v = W2[gn];
        const float b1v = b1[gn];
        const int g = gn >> 3;
        const float b2v = b2[g];
#pragma unroll
        for (int r = 0; r < 4; ++r) {
#pragma unroll
            for (int i = 0; i < 4; ++i) {
                const int gm = a0 + wm + r * 16 + q * 4 + i;
                float h = sigmoidf_fast(acc[r][c][i] * INV_W1SCALE + b1v);
                float v = h * w2v;
                v += __shfl_xor(v, 1, 64);
                v += __shfl_xor(v, 2, 64);
                v += __shfl_xor(v, 4, 64);
                if ((lane & 7) == 0)
                    X2[gm * H2 + g] = f2bf(sigmoidf_fast(v + b2v));
            }
        }
    }
}

// ---------------- bf16 core, BK=64 (gemm3) ----------------
template <int K>
__device__ __forceinline__ void gemm_core(const unsigned short* __restrict__ A,
                                          const unsigned short* __restrict__ Bm,
                                          unsigned short* lsA, unsigned short* lsB,
                                          int a_row0, int b_row0,
                                          int lane, int wave, int wm, int wn,
                                          f32x4 acc[4][4]) {
    const int q = lane >> 4, m16 = lane & 15;
    int gA[4], gB[4], lo[4];
#pragma unroll
    for (int i = 0; i < 4; ++i) {
        const int ch = wave * 4 + i;
        const int r  = ch * 8 + (lane >> 3);
        const int kc = ((lane & 7) - (lane >> 3)) & 7;
        gA[i] = (a_row0 + r) * K + kc * 8;
        gB[i] = (b_row0 + r) * K + kc * 8;
        lo[i] = ch * 512;
    }
    int ra[2][4], rb[2][4];
#pragma unroll
    for (int h = 0; h < 2; ++h)
#pragma unroll
        for (int t = 0; t < 4; ++t) {
            const int s = ((h * 4 + q + (m16 & 7)) & 7) * 8;
            ra[h][t] = (wm + t * 16 + m16) * BK + s;
            rb[h][t] = (wn + t * 16 + m16) * BK + s;
        }
    for (int kt = 0; kt < K / BK; ++kt) {
        __syncthreads();
        const int k0 = kt * BK;
#pragma unroll
        for (int i = 0; i < 4; ++i) {
            load_lds16(A + gA[i] + k0, lsA + lo[i]);
            load_lds16(Bm + gB[i] + k0, lsB + lo[i]);
        }
        __syncthreads();
#pragma unroll
        for (int h = 0; h < 2; ++h) {
            bf16x8 af[4], bfr[4];
#pragma unroll
            for (int t = 0; t < 4; ++t) af[t]  = *(const bf16x8*)(lsA + ra[h][t]);
#pragma unroll
            for (int t = 0; t < 4; ++t) bfr[t] = *(const bf16x8*)(lsB + rb[h][t]);
#pragma unroll
            for (int r = 0; r < 4; ++r)
#pragma unroll
                for (int c = 0; c < 4; ++c)
                    acc[r][c] = __builtin_amdgcn_mfma_f32_16x16x32_bf16(
                        af[r], bfr[c], acc[r][c], 0, 0, 0);
        }
    }
}

__global__ __launch_bounds__(256, 2) void gemm3_kernel(
    const unsigned short* __restrict__ X2,   // [16384,512] bf16
    const unsigned short* __restrict__ W3b,  // [256,512] bf16 (N,K)
    const float* __restrict__ b3,            // [256]
    float* __restrict__ Out) {               // [16384,256] f32
    __shared__ __attribute__((aligned(16))) unsigned short lsA[TILE * BK];
    __shared__ __attribute__((aligned(16))) unsigned short lsB[TILE * BK];
    const int tid = threadIdx.x, lane = tid & 63, wave = tid >> 6;
    const int wm = (wave >> 1) * 64, wn = (wave & 1) * 64;
    const int a0 = blockIdx.y * TILE;
    const int n0 = blockIdx.x * TILE;

    f32x4 acc[4][4];
#pragma unroll
    for (int r = 0; r < 4; ++r)
#pragma unroll
        for (int c = 0; c < 4; ++c) acc[r][c] = (f32x4)0.0f;

    gemm_core<H2>(X2, W3b, lsA, lsB, a0, n0, lane, wave, wm, wn, acc);

    const int q = lane >> 4, m16 = lane & 15;
#pragma unroll
    for (int c = 0; c < 4; ++c) {
        const int gn = n0 + wn + c * 16 + m16;
        const float b3v = b3[gn];
#pragma unroll
        for (int r = 0; r < 4; ++r) {
#pragma unroll
            for (int i = 0; i < 4; ++i) {
                const int gm = a0 + wm + r * 16 + q * 4 + i;
                Out[gm * DOUT + gn] = acc[r][c][i] + b3v;
            }
        }
    }
}

extern "C" void kernel_launch(void* const* d_in, const int* in_sizes, int n_in,
                              void* d_out, int out_size, void* d_ws, size_t ws_size,
                              hipStream_t stream) {
    const float* x  = (const float*)d_in[0];
    const float* W1 = (const float*)d_in[1];
    const float* b1 = (const float*)d_in[2];
    const float* W2 = (const float*)d_in[3];
    const float* b2 = (const float*)d_in[4];
    const float* W3 = (const float*)d_in[5];
    const float* b3 = (const float*)d_in[6];
    float* out = (float*)d_out;

    char* ws = (char*)d_ws;
    unsigned char*  x_q   = (unsigned char*)ws;                          // 16,777,216 B
    unsigned char*  w1_q  = (unsigned char*)(ws + 16777216);             //  4,194,304 B
    unsigned short* w3_bf = (unsigned short*)(ws + 16777216 + 4194304);  //    262,144 B
    unsigned short* x2_bf = (unsigned short*)(ws + 16777216 + 4194304 + 262144); // 16,777,216 B

    cvt3_kernel<<<(NX4 + NW14 + NW34) / 256, 256, 0, stream>>>(
        x, W1, W3, (unsigned int*)x_q, (unsigned int*)w1_q, w3_bf);

    // GEMM1 (MX-fp8, 8 waves) + fused layer 2: 1-D grid, XCD-aware decode inside
    gemm1_fused<<<(B_ROWS / TILE) * (H1 / TILE), 512, 0, stream>>>(
        x_q, w1_q, b1, W2, b2, x2_bf);

    // GEMM3 (bf16): grid = (2, 128)
    gemm3_kernel<<<dim3(DOUT / TILE, B_ROWS / TILE), 256, 0, stream>>>(
        x2_bf, w3_bf, b3, out);
}

// Round 5
// 233.485 us; speedup vs baseline: 7.7286x; 7.7286x over previous
//
#include <hip/hip_runtime.h>
#include <cstdint>

// AdaptiveNet: x[16384,1024] -> fc1(4096)+sigmoid -> grouped(512 g of 8)+sigmoid -> fc3(256)
// R5: fp8-e4m3 GEMM1 (W1 x64, acc/64), BK=128, 164us total 275us. VGPR=64 (acc in AGPRs).
// R6-R9: every mfma_scale_f32_16x16x128_f8f6f4 configuration spills or caps occupancy
//     (R6 spill 1086us; R7 256-VGPR 378us; R9 64-VGPR+2.7KB/thread scratch 1705us);
//     inline-asm non-scaled form killed the container (R8). K=128 path binned.
// R10: R5 core restored + epilogue rework. R5 counters: VALUBusy 60% > MfmaUtil 36%,
//     driven by 192 shfl_xor/thread in the grouped-reduce. Swap MFMA operands
//     (mfma(W1frag, Xfrag)) so h-cols land on the register axis (row=q*4+i) and
//     batch on the lane axis (col=m16): group-of-8 reduce = 4 in-reg FMA + ONE
//     shfl_xor(16) per 4 acc elems -> 16 shfl/thread (12x cut). b1/W2 as float4.
//     K-loop byte-identical to R5 otherwise; acc stays in AGPRs.

#define B_ROWS 16384
#define DIN 1024
#define H1  4096
#define H2  512
#define DOUT 256
#define TILE 128
#define BK 64          // bf16 core (gemm3)
#define BK1 128        // fp8 core (gemm1)
#define INV_W1SCALE 0.015625f   // 1/64

#define NX4  (B_ROWS * DIN / 4)   // 4194304
#define NW14 (H1 * DIN / 4)       // 1048576
#define NW34 (DOUT * H2 / 4)      // 32768

typedef __bf16 bf16x8 __attribute__((ext_vector_type(8)));
typedef float f32x4 __attribute__((ext_vector_type(4)));

__device__ __forceinline__ unsigned short f2bf(float f) {
    union { float f; uint32_t u; } v; v.f = f;
    uint32_t u = v.u;
    u += 0x7FFFu + ((u >> 16) & 1u);   // round-to-nearest-even
    return (unsigned short)(u >> 16);
}

__device__ __forceinline__ float sigmoidf_fast(float x) {
    return 1.0f / (1.0f + __expf(-x));
}

// x -> fp8 (x1), W1 -> fp8 (x64), W3 -> bf16, one launch
__global__ __launch_bounds__(256) void cvt3_kernel(
    const float* __restrict__ x, const float* __restrict__ w1,
    const float* __restrict__ w3, unsigned int* __restrict__ xo,
    unsigned int* __restrict__ w1o, unsigned short* __restrict__ w3o) {
    int i = blockIdx.x * 256 + threadIdx.x;
    if (i < NX4) {
        float4 v = ((const float4*)x)[i];
        unsigned int p = 0;
        p = __builtin_amdgcn_cvt_pk_fp8_f32(v.x, v.y, p, false);
        p = __builtin_amdgcn_cvt_pk_fp8_f32(v.z, v.w, p, true);
        xo[i] = p;
    } else if (i < NX4 + NW14) {
        int j = i - NX4;
        float4 v = ((const float4*)w1)[j];
        unsigned int p = 0;
        p = __builtin_amdgcn_cvt_pk_fp8_f32(v.x * 64.0f, v.y * 64.0f, p, false);
        p = __builtin_amdgcn_cvt_pk_fp8_f32(v.z * 64.0f, v.w * 64.0f, p, true);
        w1o[j] = p;
    } else {
        int j = i - NX4 - NW14;
        float4 v = ((const float4*)w3)[j];
        ushort4 o;
        o.x = f2bf(v.x); o.y = f2bf(v.y); o.z = f2bf(v.z); o.w = f2bf(v.w);
        ((ushort4*)w3o)[j] = o;
    }
}

__device__ __forceinline__ void load_lds16(const void* g, void* l) {
    __builtin_amdgcn_global_load_lds(
        (const __attribute__((address_space(1))) void*)g,
        (__attribute__((address_space(3))) void*)l, 16, 0, 0);
}

// ---------------- fp8 core, BK1=128, tile 128x128 ----------------
// LDS row = 128 fp8 = 128B = 8 chunks of 16B, chunk slots rotated by (row&7).
// A/B-frag (16x16x32 fp8): lane(q=l>>4,m=l&15) holds 8 consecutive fp8 at k=q*8
// within each k32 sub-chunk s; byte addr = row*128 + slot(2s+(q>>1))*16 + (q&1)*8.
// MFMA called as mfma(W1frag, Xfrag): D[row=h-col (q*4+i)][col=batch (m16)].
__global__ __launch_bounds__(256, 2) void gemm1_fused(
    const unsigned char* __restrict__ Xq,    // [16384,1024] fp8
    const unsigned char* __restrict__ W1q,   // [4096,1024]  fp8 (N,K), x64
    const float* __restrict__ b1,            // [4096]
    const float* __restrict__ W2,            // [512*8] flat; W2[g][s] = W2[gn]
    const float* __restrict__ b2,            // [512]
    unsigned short* __restrict__ X2) {       // [16384,512] bf16
    __shared__ __attribute__((aligned(16))) unsigned char lsA[TILE * BK1];
    __shared__ __attribute__((aligned(16))) unsigned char lsB[TILE * BK1];
    const int tid = threadIdx.x, lane = tid & 63, wave = tid >> 6;
    const int wm = (wave >> 1) * 64, wn = (wave & 1) * 64;

    // XCD-aware decode (R4): xcd owns a 512-col W1 slice (L2-resident)
    const int bid = blockIdx.x;
    const int xcd = bid & 7;
    const int local = bid >> 3;
    const int n0 = (xcd * 4 + (local & 3)) * TILE;
    const int a0 = (local >> 2) * TILE;

    const int q = lane >> 4, m16 = lane & 15;

    // staging: 4 chunks of 1KB per matrix per wave; chunk = 8 rows x 128B
    int gA[4], gB[4], lo[4];
#pragma unroll
    for (int i = 0; i < 4; ++i) {
        const int ch = wave * 4 + i;
        const int r  = ch * 8 + (lane >> 3);
        const int kc = ((lane & 7) - (lane >> 3)) & 7;
        gA[i] = (a0 + r) * DIN + kc * 16;
        gB[i] = (n0 + r) * DIN + kc * 16;
        lo[i] = ch * 1024;
    }
    // fragment offsets: rowbase (t) + slotoff (s)
    int rowA[4], rowB[4], so[4];
#pragma unroll
    for (int t = 0; t < 4; ++t) {
        rowA[t] = (wm + t * 16 + m16) * BK1 + (q & 1) * 8;
        rowB[t] = (wn + t * 16 + m16) * BK1 + (q & 1) * 8;
    }
#pragma unroll
    for (int s = 0; s < 4; ++s)
        so[s] = ((s * 2 + (q >> 1) + (m16 & 7)) & 7) * 16;

    // acc[t][u]: t = W1 16-block (h cols), u = X 16-block (batch rows)
    f32x4 acc[4][4];
#pragma unroll
    for (int r = 0; r < 4; ++r)
#pragma unroll
        for (int c = 0; c < 4; ++c) acc[r][c] = (f32x4)0.0f;

    for (int kt = 0; kt < DIN / BK1; ++kt) {
        __syncthreads();
        const int k0 = kt * BK1;
#pragma unroll
        for (int i = 0; i < 4; ++i) {
            load_lds16(Xq + gA[i] + k0, lsA + lo[i]);
            load_lds16(W1q + gB[i] + k0, lsB + lo[i]);
        }
        __syncthreads();
#pragma unroll
        for (int s = 0; s < 4; ++s) {
            long fw[4], fx[4];
#pragma unroll
            for (int t = 0; t < 4; ++t) fw[t] = *(const long*)(lsB + rowB[t] + so[s]);
#pragma unroll
            for (int t = 0; t < 4; ++t) fx[t] = *(const long*)(lsA + rowA[t] + so[s]);
#pragma unroll
            for (int t = 0; t < 4; ++t)
#pragma unroll
                for (int u = 0; u < 4; ++u)
                    acc[t][u] = __builtin_amdgcn_mfma_f32_16x16x32_fp8_fp8(
                        fw[t], fx[u], acc[t][u], 0, 0, 0);
        }
    }

    // Epilogue. D[row = h-col offset (q*4+i)][col = batch (m16)]. acc is 64x true z1.
    // Group-of-8 reduce: 4 in-reg FMAs + one shfl_xor(16) joining q<->q^1.
#pragma unroll
    for (int t = 0; t < 4; ++t) {
        const int nb = n0 + wn + t * 16 + q * 4;      // this lane's first h col
        const float4 b1v = *(const float4*)(b1 + nb);
        const float4 w2v = *(const float4*)(W2 + nb);
        const int g = nb >> 3;                         // same for paired lanes q,q^1
        const float b2v = b2[g];
#pragma unroll
        for (int u = 0; u < 4; ++u) {
            const int gm = a0 + wm + u * 16 + m16;     // batch row
            const float h0 = sigmoidf_fast(acc[t][u][0] * INV_W1SCALE + b1v.x);
            const float h1 = sigmoidf_fast(acc[t][u][1] * INV_W1SCALE + b1v.y);
            const float h2 = sigmoidf_fast(acc[t][u][2] * INV_W1SCALE + b1v.z);
            const float h3 = sigmoidf_fast(acc[t][u][3] * INV_W1SCALE + b1v.w);
            float v = h0 * w2v.x + h1 * w2v.y + h2 * w2v.z + h3 * w2v.w;
            v += __shfl_xor(v, 16, 64);
            if ((q & 1) == 0)
                X2[gm * H2 + g] = f2bf(sigmoidf_fast(v + b2v));
        }
    }
}

// ---------------- bf16 core, BK=64 (gemm3) ----------------
template <int K>
__device__ __forceinline__ void gemm_core(const unsigned short* __restrict__ A,
                                          const unsigned short* __restrict__ Bm,
                                          unsigned short* lsA, unsigned short* lsB,
                                          int a_row0, int b_row0,
                                          int lane, int wave, int wm, int wn,
                                          f32x4 acc[4][4]) {
    const int q = lane >> 4, m16 = lane & 15;
    int gA[4], gB[4], lo[4];
#pragma unroll
    for (int i = 0; i < 4; ++i) {
        const int ch = wave * 4 + i;
        const int r  = ch * 8 + (lane >> 3);
        const int kc = ((lane & 7) - (lane >> 3)) & 7;
        gA[i] = (a_row0 + r) * K + kc * 8;
        gB[i] = (b_row0 + r) * K + kc * 8;
        lo[i] = ch * 512;
    }
    int ra[2][4], rb[2][4];
#pragma unroll
    for (int h = 0; h < 2; ++h)
#pragma unroll
        for (int t = 0; t < 4; ++t) {
            const int s = ((h * 4 + q + (m16 & 7)) & 7) * 8;
            ra[h][t] = (wm + t * 16 + m16) * BK + s;
            rb[h][t] = (wn + t * 16 + m16) * BK + s;
        }
    for (int kt = 0; kt < K / BK; ++kt) {
        __syncthreads();
        const int k0 = kt * BK;
#pragma unroll
        for (int i = 0; i < 4; ++i) {
            load_lds16(A + gA[i] + k0, lsA + lo[i]);
            load_lds16(Bm + gB[i] + k0, lsB + lo[i]);
        }
        __syncthreads();
#pragma unroll
        for (int h = 0; h < 2; ++h) {
            bf16x8 af[4], bfr[4];
#pragma unroll
            for (int t = 0; t < 4; ++t) af[t]  = *(const bf16x8*)(lsA + ra[h][t]);
#pragma unroll
            for (int t = 0; t < 4; ++t) bfr[t] = *(const bf16x8*)(lsB + rb[h][t]);
#pragma unroll
            for (int r = 0; r < 4; ++r)
#pragma unroll
                for (int c = 0; c < 4; ++c)
                    acc[r][c] = __builtin_amdgcn_mfma_f32_16x16x32_bf16(
                        af[r], bfr[c], acc[r][c], 0, 0, 0);
        }
    }
}

__global__ __launch_bounds__(256, 2) void gemm3_kernel(
    const unsigned short* __restrict__ X2,   // [16384,512] bf16
    const unsigned short* __restrict__ W3b,  // [256,512] bf16 (N,K)
    const float* __restrict__ b3,            // [256]
    float* __restrict__ Out) {               // [16384,256] f32
    __shared__ __attribute__((aligned(16))) unsigned short lsA[TILE * BK];
    __shared__ __attribute__((aligned(16))) unsigned short lsB[TILE * BK];
    const int tid = threadIdx.x, lane = tid & 63, wave = tid >> 6;
    const int wm = (wave >> 1) * 64, wn = (wave & 1) * 64;
    const int a0 = blockIdx.y * TILE;
    const int n0 = blockIdx.x * TILE;

    f32x4 acc[4][4];
#pragma unroll
    for (int r = 0; r < 4; ++r)
#pragma unroll
        for (int c = 0; c < 4; ++c) acc[r][c] = (f32x4)0.0f;

    gemm_core<H2>(X2, W3b, lsA, lsB, a0, n0, lane, wave, wm, wn, acc);

    const int q = lane >> 4, m16 = lane & 15;
#pragma unroll
    for (int c = 0; c < 4; ++c) {
        const int gn = n0 + wn + c * 16 + m16;
        const float b3v = b3[gn];
#pragma unroll
        for (int r = 0; r < 4; ++r) {
#pragma unroll
            for (int i = 0; i < 4; ++i) {
                const int gm = a0 + wm + r * 16 + q * 4 + i;
                Out[gm * DOUT + gn] = acc[r][c][i] + b3v;
            }
        }
    }
}

extern "C" void kernel_launch(void* const* d_in, const int* in_sizes, int n_in,
                              void* d_out, int out_size, void* d_ws, size_t ws_size,
                              hipStream_t stream) {
    const float* x  = (const float*)d_in[0];
    const float* W1 = (const float*)d_in[1];
    const float* b1 = (const float*)d_in[2];
    const float* W2 = (const float*)d_in[3];
    const float* b2 = (const float*)d_in[4];
    const float* W3 = (const float*)d_in[5];
    const float* b3 = (const float*)d_in[6];
    float* out = (float*)d_out;

    char* ws = (char*)d_ws;
    unsigned char*  x_q   = (unsigned char*)ws;                          // 16,777,216 B
    unsigned char*  w1_q  = (unsigned char*)(ws + 16777216);             //  4,194,304 B
    unsigned short* w3_bf = (unsigned short*)(ws + 16777216 + 4194304);  //    262,144 B
    unsigned short* x2_bf = (unsigned short*)(ws + 16777216 + 4194304 + 262144); // 16,777,216 B

    cvt3_kernel<<<(NX4 + NW14 + NW34) / 256, 256, 0, stream>>>(
        x, W1, W3, (unsigned int*)x_q, (unsigned int*)w1_q, w3_bf);

    // GEMM1 (fp8) + fused layer 2: 1-D grid, XCD-aware decode inside
    gemm1_fused<<<(B_ROWS / TILE) * (H1 / TILE), 256, 0, stream>>>(
        x_q, w1_q, b1, W2, b2, x2_bf);

    // GEMM3 (bf16): grid = (2, 128)
    gemm3_kernel<<<dim3(DOUT / TILE, B_ROWS / TILE), 256, 0, stream>>>(
        x2_bf, w3_bf, b3, out);
}

// Round 6
// 233.256 us; speedup vs baseline: 7.7361x; 1.0010x over previous
//
#include <hip/hip_runtime.h>
#include <cstdint>

// AdaptiveNet: x[16384,1024] -> fc1(4096)+sigmoid -> grouped(512 g of 8)+sigmoid -> fc3(256)
// R5: fp8-e4m3 GEMM1 (W1 x64, acc/64), BK=128, gemm1 164us / total 275us.
// R6-R9: all mfma_scale K=128 configs spill or cap occupancy; K=128 path binned.
// R10: operand-swapped epilogue (mfma(W1frag,Xfrag): h-cols on register axis) ->
//     grouped reduce = 4 FMA + 1 shfl_xor(16) per 4 elems (192->16 shuffles).
//     gemm1 116us, MfmaUtil 54%, total 233.5us. VERIFIED.
// R11: tail round, gemm1 untouched. (a) cvt3: 20608 single-shot blocks -> 2048
//     blocks + grid-stride (G11: launch-overhead cap). (b) gemm3: grid (2,128)
//     = 1 block/CU had zero inter-block latency hiding; TILE_M 128->64 ->
//     grid (2,256) = 2 blocks/CU, LDS 24KB, same per-row staging geometry
//     (chunks: A 2/wave, B 4/wave), acc[2][4]. Summation order preserved.

#define B_ROWS 16384
#define DIN 1024
#define H1  4096
#define H2  512
#define DOUT 256
#define TILE 128
#define TM3 64         // gemm3 M-tile (R11)
#define BK 64          // bf16 core (gemm3)
#define BK1 128        // fp8 core (gemm1)
#define INV_W1SCALE 0.015625f   // 1/64
#define CVT_BLOCKS 2048

#define NX4  (B_ROWS * DIN / 4)   // 4194304
#define NW14 (H1 * DIN / 4)       // 1048576
#define NW34 (DOUT * H2 / 4)      // 32768

typedef __bf16 bf16x8 __attribute__((ext_vector_type(8)));
typedef float f32x4 __attribute__((ext_vector_type(4)));

__device__ __forceinline__ unsigned short f2bf(float f) {
    union { float f; uint32_t u; } v; v.f = f;
    uint32_t u = v.u;
    u += 0x7FFFu + ((u >> 16) & 1u);   // round-to-nearest-even
    return (unsigned short)(u >> 16);
}

__device__ __forceinline__ float sigmoidf_fast(float x) {
    return 1.0f / (1.0f + __expf(-x));
}

// x -> fp8 (x1), W1 -> fp8 (x64), W3 -> bf16. Grid-stride over all three regions.
__global__ __launch_bounds__(256) void cvt3_kernel(
    const float* __restrict__ x, const float* __restrict__ w1,
    const float* __restrict__ w3, unsigned int* __restrict__ xo,
    unsigned int* __restrict__ w1o, unsigned short* __restrict__ w3o) {
    const int TOT = NX4 + NW14 + NW34;
    for (int i = blockIdx.x * 256 + threadIdx.x; i < TOT; i += CVT_BLOCKS * 256) {
        if (i < NX4) {
            float4 v = ((const float4*)x)[i];
            unsigned int p = 0;
            p = __builtin_amdgcn_cvt_pk_fp8_f32(v.x, v.y, p, false);
            p = __builtin_amdgcn_cvt_pk_fp8_f32(v.z, v.w, p, true);
            xo[i] = p;
        } else if (i < NX4 + NW14) {
            int j = i - NX4;
            float4 v = ((const float4*)w1)[j];
            unsigned int p = 0;
            p = __builtin_amdgcn_cvt_pk_fp8_f32(v.x * 64.0f, v.y * 64.0f, p, false);
            p = __builtin_amdgcn_cvt_pk_fp8_f32(v.z * 64.0f, v.w * 64.0f, p, true);
            w1o[j] = p;
        } else {
            int j = i - NX4 - NW14;
            float4 v = ((const float4*)w3)[j];
            ushort4 o;
            o.x = f2bf(v.x); o.y = f2bf(v.y); o.z = f2bf(v.z); o.w = f2bf(v.w);
            ((ushort4*)w3o)[j] = o;
        }
    }
}

__device__ __forceinline__ void load_lds16(const void* g, void* l) {
    __builtin_amdgcn_global_load_lds(
        (const __attribute__((address_space(1))) void*)g,
        (__attribute__((address_space(3))) void*)l, 16, 0, 0);
}

// ---------------- fp8 core, BK1=128, tile 128x128 (gemm1, R10-verified) ----------------
// LDS row = 128 fp8 = 128B = 8 chunks of 16B, chunk slots rotated by (row&7).
// A/B-frag (16x16x32 fp8): lane(q=l>>4,m=l&15) holds 8 consecutive fp8 at k=q*8
// within each k32 sub-chunk s; byte addr = row*128 + slot(2s+(q>>1))*16 + (q&1)*8.
// MFMA called as mfma(W1frag, Xfrag): D[row=h-col (q*4+i)][col=batch (m16)].
__global__ __launch_bounds__(256, 2) void gemm1_fused(
    const unsigned char* __restrict__ Xq,    // [16384,1024] fp8
    const unsigned char* __restrict__ W1q,   // [4096,1024]  fp8 (N,K), x64
    const float* __restrict__ b1,            // [4096]
    const float* __restrict__ W2,            // [512*8] flat; W2[g][s] = W2[gn]
    const float* __restrict__ b2,            // [512]
    unsigned short* __restrict__ X2) {       // [16384,512] bf16
    __shared__ __attribute__((aligned(16))) unsigned char lsA[TILE * BK1];
    __shared__ __attribute__((aligned(16))) unsigned char lsB[TILE * BK1];
    const int tid = threadIdx.x, lane = tid & 63, wave = tid >> 6;
    const int wm = (wave >> 1) * 64, wn = (wave & 1) * 64;

    // XCD-aware decode (R4): xcd owns a 512-col W1 slice (L2-resident)
    const int bid = blockIdx.x;
    const int xcd = bid & 7;
    const int local = bid >> 3;
    const int n0 = (xcd * 4 + (local & 3)) * TILE;
    const int a0 = (local >> 2) * TILE;

    const int q = lane >> 4, m16 = lane & 15;

    // staging: 4 chunks of 1KB per matrix per wave; chunk = 8 rows x 128B
    int gA[4], gB[4], lo[4];
#pragma unroll
    for (int i = 0; i < 4; ++i) {
        const int ch = wave * 4 + i;
        const int r  = ch * 8 + (lane >> 3);
        const int kc = ((lane & 7) - (lane >> 3)) & 7;
        gA[i] = (a0 + r) * DIN + kc * 16;
        gB[i] = (n0 + r) * DIN + kc * 16;
        lo[i] = ch * 1024;
    }
    // fragment offsets: rowbase (t) + slotoff (s)
    int rowA[4], rowB[4], so[4];
#pragma unroll
    for (int t = 0; t < 4; ++t) {
        rowA[t] = (wm + t * 16 + m16) * BK1 + (q & 1) * 8;
        rowB[t] = (wn + t * 16 + m16) * BK1 + (q & 1) * 8;
    }
#pragma unroll
    for (int s = 0; s < 4; ++s)
        so[s] = ((s * 2 + (q >> 1) + (m16 & 7)) & 7) * 16;

    // acc[t][u]: t = W1 16-block (h cols), u = X 16-block (batch rows)
    f32x4 acc[4][4];
#pragma unroll
    for (int r = 0; r < 4; ++r)
#pragma unroll
        for (int c = 0; c < 4; ++c) acc[r][c] = (f32x4)0.0f;

    for (int kt = 0; kt < DIN / BK1; ++kt) {
        __syncthreads();
        const int k0 = kt * BK1;
#pragma unroll
        for (int i = 0; i < 4; ++i) {
            load_lds16(Xq + gA[i] + k0, lsA + lo[i]);
            load_lds16(W1q + gB[i] + k0, lsB + lo[i]);
        }
        __syncthreads();
#pragma unroll
        for (int s = 0; s < 4; ++s) {
            long fw[4], fx[4];
#pragma unroll
            for (int t = 0; t < 4; ++t) fw[t] = *(const long*)(lsB + rowB[t] + so[s]);
#pragma unroll
            for (int t = 0; t < 4; ++t) fx[t] = *(const long*)(lsA + rowA[t] + so[s]);
#pragma unroll
            for (int t = 0; t < 4; ++t)
#pragma unroll
                for (int u = 0; u < 4; ++u)
                    acc[t][u] = __builtin_amdgcn_mfma_f32_16x16x32_fp8_fp8(
                        fw[t], fx[u], acc[t][u], 0, 0, 0);
        }
    }

    // Epilogue. D[row = h-col offset (q*4+i)][col = batch (m16)]. acc is 64x true z1.
    // Group-of-8 reduce: 4 in-reg FMAs + one shfl_xor(16) joining q<->q^1.
#pragma unroll
    for (int t = 0; t < 4; ++t) {
        const int nb = n0 + wn + t * 16 + q * 4;      // this lane's first h col
        const float4 b1v = *(const float4*)(b1 + nb);
        const float4 w2v = *(const float4*)(W2 + nb);
        const int g = nb >> 3;                         // same for paired lanes q,q^1
        const float b2v = b2[g];
#pragma unroll
        for (int u = 0; u < 4; ++u) {
            const int gm = a0 + wm + u * 16 + m16;     // batch row
            const float h0 = sigmoidf_fast(acc[t][u][0] * INV_W1SCALE + b1v.x);
            const float h1 = sigmoidf_fast(acc[t][u][1] * INV_W1SCALE + b1v.y);
            const float h2 = sigmoidf_fast(acc[t][u][2] * INV_W1SCALE + b1v.z);
            const float h3 = sigmoidf_fast(acc[t][u][3] * INV_W1SCALE + b1v.w);
            float v = h0 * w2v.x + h1 * w2v.y + h2 * w2v.z + h3 * w2v.w;
            v += __shfl_xor(v, 16, 64);
            if ((q & 1) == 0)
                X2[gm * H2 + g] = f2bf(sigmoidf_fast(v + b2v));
        }
    }
}

// ---------------- bf16 core, BK=64, M-tile 64 (gemm3, R11) ----------------
// Same per-row byte geometry as before (chunk = 8 rows x 128B, rotation by row&7);
// only chunk counts change: A = 8 chunks (2/wave), B = 16 chunks (4/wave).
// Wave grid 2x2: per-wave output 32x64, acc[2][4].
__global__ __launch_bounds__(256, 2) void gemm3_kernel(
    const unsigned short* __restrict__ X2,   // [16384,512] bf16
    const unsigned short* __restrict__ W3b,  // [256,512] bf16 (N,K)
    const float* __restrict__ b3,            // [256]
    float* __restrict__ Out) {               // [16384,256] f32
    __shared__ __attribute__((aligned(16))) unsigned short lsA[TM3 * BK];    // 8KB
    __shared__ __attribute__((aligned(16))) unsigned short lsB[TILE * BK];   // 16KB
    const int tid = threadIdx.x, lane = tid & 63, wave = tid >> 6;
    const int wm = (wave >> 1) * 32, wn = (wave & 1) * 64;
    const int m0 = blockIdx.y * TM3;
    const int n0 = blockIdx.x * TILE;
    const int q = lane >> 4, m16 = lane & 15;

    // staging: A 2 chunks/wave (ch 0..7), B 4 chunks/wave (ch 0..15)
    int gA[2], loA[2], gB[4], loB[4];
#pragma unroll
    for (int i = 0; i < 2; ++i) {
        const int ch = wave * 2 + i;
        const int r  = ch * 8 + (lane >> 3);
        const int kc = ((lane & 7) - (lane >> 3)) & 7;
        gA[i]  = (m0 + r) * H2 + kc * 8;
        loA[i] = ch * 512;
    }
#pragma unroll
    for (int i = 0; i < 4; ++i) {
        const int ch = wave * 4 + i;
        const int r  = ch * 8 + (lane >> 3);
        const int kc = ((lane & 7) - (lane >> 3)) & 7;
        gB[i]  = (n0 + r) * H2 + kc * 8;
        loB[i] = ch * 512;
    }
    int ra[2][2], rb[2][4];
#pragma unroll
    for (int h = 0; h < 2; ++h) {
        const int s = ((h * 4 + q + (m16 & 7)) & 7) * 8;
#pragma unroll
        for (int t = 0; t < 2; ++t) ra[h][t] = (wm + t * 16 + m16) * BK + s;
#pragma unroll
        for (int t = 0; t < 4; ++t) rb[h][t] = (wn + t * 16 + m16) * BK + s;
    }

    f32x4 acc[2][4];
#pragma unroll
    for (int r = 0; r < 2; ++r)
#pragma unroll
        for (int c = 0; c < 4; ++c) acc[r][c] = (f32x4)0.0f;

    for (int kt = 0; kt < H2 / BK; ++kt) {
        __syncthreads();
        const int k0 = kt * BK;
#pragma unroll
        for (int i = 0; i < 2; ++i) load_lds16(X2 + gA[i] + k0, lsA + loA[i]);
#pragma unroll
        for (int i = 0; i < 4; ++i) load_lds16(W3b + gB[i] + k0, lsB + loB[i]);
        __syncthreads();
#pragma unroll
        for (int h = 0; h < 2; ++h) {
            bf16x8 af[2], bfr[4];
#pragma unroll
            for (int t = 0; t < 2; ++t) af[t]  = *(const bf16x8*)(lsA + ra[h][t]);
#pragma unroll
            for (int t = 0; t < 4; ++t) bfr[t] = *(const bf16x8*)(lsB + rb[h][t]);
#pragma unroll
            for (int r = 0; r < 2; ++r)
#pragma unroll
                for (int c = 0; c < 4; ++c)
                    acc[r][c] = __builtin_amdgcn_mfma_f32_16x16x32_bf16(
                        af[r], bfr[c], acc[r][c], 0, 0, 0);
        }
    }

    // Epilogue: col = lane&15 (n), row = q*4+i (m).
#pragma unroll
    for (int c = 0; c < 4; ++c) {
        const int gn = n0 + wn + c * 16 + m16;
        const float b3v = b3[gn];
#pragma unroll
        for (int r = 0; r < 2; ++r) {
#pragma unroll
            for (int i = 0; i < 4; ++i) {
                const int gm = m0 + wm + r * 16 + q * 4 + i;
                Out[gm * DOUT + gn] = acc[r][c][i] + b3v;
            }
        }
    }
}

extern "C" void kernel_launch(void* const* d_in, const int* in_sizes, int n_in,
                              void* d_out, int out_size, void* d_ws, size_t ws_size,
                              hipStream_t stream) {
    const float* x  = (const float*)d_in[0];
    const float* W1 = (const float*)d_in[1];
    const float* b1 = (const float*)d_in[2];
    const float* W2 = (const float*)d_in[3];
    const float* b2 = (const float*)d_in[4];
    const float* W3 = (const float*)d_in[5];
    const float* b3 = (const float*)d_in[6];
    float* out = (float*)d_out;

    char* ws = (char*)d_ws;
    unsigned char*  x_q   = (unsigned char*)ws;                          // 16,777,216 B
    unsigned char*  w1_q  = (unsigned char*)(ws + 16777216);             //  4,194,304 B
    unsigned short* w3_bf = (unsigned short*)(ws + 16777216 + 4194304);  //    262,144 B
    unsigned short* x2_bf = (unsigned short*)(ws + 16777216 + 4194304 + 262144); // 16,777,216 B

    // Conversions: grid-stride, 2048 blocks (G11)
    cvt3_kernel<<<CVT_BLOCKS, 256, 0, stream>>>(
        x, W1, W3, (unsigned int*)x_q, (unsigned int*)w1_q, w3_bf);

    // GEMM1 (fp8) + fused layer 2: 1-D grid, XCD-aware decode inside
    gemm1_fused<<<(B_ROWS / TILE) * (H1 / TILE), 256, 0, stream>>>(
        x_q, w1_q, b1, W2, b2, x2_bf);

    // GEMM3 (bf16): grid = (2, 256), 2 blocks/CU
    gemm3_kernel<<<dim3(DOUT / TILE, B_ROWS / TM3), 256, 0, stream>>>(
        x2_bf, w3_bf, b3, out);
}